// Round 3
// baseline (612.256 us; speedup 1.0000x reference)
//
#include <hip/hip_runtime.h>
#include <math.h>

#define SCALE_F 0.0721687836487032f  // 192^-0.5

typedef __attribute__((ext_vector_type(8))) short bf16x8;
typedef __attribute__((ext_vector_type(4))) float f32x4;
typedef __attribute__((ext_vector_type(4))) unsigned short u16x4;

static __device__ __forceinline__ short f2bf(float f) {
  unsigned u = __float_as_uint(f);
  u += 0x7fffu + ((u >> 16) & 1u);   // RNE
  return (short)(u >> 16);
}

// async global->LDS, 16B per lane (m97-verified path)
static __device__ __forceinline__ void gl_lds16(const void* g, void* l) {
  __builtin_amdgcn_global_load_lds((const __attribute__((address_space(1))) void*)g,
                                   (__attribute__((address_space(3))) void*)l, 16, 0, 0);
}

// ---------------------------------------------------------------------------
// bf16 MFMA GEMM (m97 structure, lane-linear frag staging = conflict-free
// ds_read_b128): C[M,N] = A[M,K] @ W[N,K]^T
// LDS frag layout: 8 frags of 1KB per operand; frag rb holds rows rb*16..+15,
// byte lane*16 of frag rb = A[rb*16 + (lane&15)][kchunk (lane>>4)] -> read
// address frag*1024 + lane*16 is linear in lane (zero bank conflicts).
// MODE 0: fp32 out row-major [M][N]
// MODE 2: q_up fused rope+scale+pack -> Qb (b,h,s,192) bf16   (N=3072)
// MODE 3: kv_up fused split -> Kb (b,h,s,192) nope cols + Vt (b,h,128,2048)
// ---------------------------------------------------------------------------
template <int MODE>
__global__ __launch_bounds__(256) void gemm_mfma(
    const short* __restrict__ A, const short* __restrict__ W,
    void* __restrict__ Cout, int N, int K,
    const float* __restrict__ cosb, const float* __restrict__ sinb,
    short* __restrict__ out2)
{
  __shared__ __align__(16) short As[128 * 32];
  __shared__ __align__(16) short Ws[128 * 32];
  const int tid = threadIdx.x;
  const int lane = tid & 63;
  const int quad = lane >> 4, n16 = lane & 15;
  const int bm = blockIdx.y * 128, bn = blockIdx.x * 128;
  const int wr = ((tid >> 6) >> 1) * 64, wc = ((tid >> 6) & 1) * 64;

  f32x4 acc[4][4];
  #pragma unroll
  for (int i = 0; i < 4; ++i)
    #pragma unroll
    for (int j = 0; j < 4; ++j) acc[i][j] = (f32x4){0.f, 0.f, 0.f, 0.f};

  // lane-linear frag staging: src row = frag*16 + (lane&15), col chunk lane>>4
  const int sw = tid >> 6;           // wave = frag row-block (0..3)
  const int sr = lane & 15, sc = (lane >> 4) * 8;
  const short* a0p = A + (size_t)(bm + sw * 16 + sr) * K + sc;
  const short* a1p = A + (size_t)(bm + 64 + sw * 16 + sr) * K + sc;
  const short* w0p = W + (size_t)(bn + sw * 16 + sr) * K + sc;
  const short* w1p = W + (size_t)(bn + 64 + sw * 16 + sr) * K + sc;
  short* asd0 = &As[tid * 8];
  short* asd1 = &As[2048 + tid * 8];
  short* wsd0 = &Ws[tid * 8];
  short* wsd1 = &Ws[2048 + tid * 8];

  for (int k0 = 0; k0 < K; k0 += 32) {
    gl_lds16(a0p, asd0);
    gl_lds16(a1p, asd1);
    gl_lds16(w0p, wsd0);
    gl_lds16(w1p, wsd1);
    a0p += 32; a1p += 32; w0p += 32; w1p += 32;
    __syncthreads();

    bf16x8 af[4], wf[4];
    #pragma unroll
    for (int i = 0; i < 4; ++i) {
      af[i] = *(const bf16x8*)&As[((wr >> 4) + i) * 512 + lane * 8];
      wf[i] = *(const bf16x8*)&Ws[((wc >> 4) + i) * 512 + lane * 8];
    }
    #pragma unroll
    for (int i = 0; i < 4; ++i)
      #pragma unroll
      for (int j = 0; j < 4; ++j)
        acc[i][j] = __builtin_amdgcn_mfma_f32_16x16x32_bf16(af[i], wf[j], acc[i][j], 0, 0, 0);
    __syncthreads();
  }

  if (MODE == 0) {
    #pragma unroll
    for (int i = 0; i < 4; ++i)
      #pragma unroll
      for (int r = 0; r < 4; ++r) {
        size_t row = (size_t)(bm + wr + i * 16 + quad * 4 + r);
        #pragma unroll
        for (int j = 0; j < 4; ++j)
          ((float*)Cout)[row * N + bn + wc + j * 16 + n16] = acc[i][j][r];
      }
  } else if (MODE == 2) {
    // q_up: rope last 64 of each 192-head, scale, pack to (b,h,s,192)
    #pragma unroll
    for (int i = 0; i < 4; ++i)
      #pragma unroll
      for (int r = 0; r < 4; ++r) {
        int m = bm + wr + i * 16 + quad * 4 + r;
        int bb = m >> 11, s = m & 2047;
        #pragma unroll
        for (int j = 0; j < 4; ++j) {
          int col = bn + wc + j * 16 + n16;
          int h = col / 192, c = col - h * 192;
          float v = acc[i][j][r];
          if (c >= 128) {
            int jr = c - 128;
            float part = acc[i][j ^ 2][r];   // partner col = col +/- 32 (in-wave)
            float cs = cosb[(size_t)m * 64 + jr], sn = sinb[(size_t)m * 64 + jr];
            v = (jr < 32) ? (v * cs - part * sn) : (v * cs + part * sn);
          }
          ((short*)Cout)[(((size_t)(bb * 16 + h)) * 2048 + s) * 192 + c] = f2bf(v * SCALE_F);
        }
      }
  } else {
    // kv_up: N=4096, head = col>>8; c<128 -> Kb nope, c>=128 -> Vt transposed
    #pragma unroll
    for (int i = 0; i < 4; ++i)
      #pragma unroll
      for (int r = 0; r < 4; ++r) {
        int m = bm + wr + i * 16 + quad * 4 + r;
        int bb = m >> 11, s = m & 2047;
        #pragma unroll
        for (int j = 0; j < 4; ++j) {
          int col = bn + wc + j * 16 + n16;
          int h = col >> 8, c = col & 255;
          short v = f2bf(acc[i][j][r]);
          if (c < 128)
            ((short*)Cout)[(((size_t)(bb * 16 + h)) * 2048 + s) * 192 + c] = v;
          else
            out2[((size_t)(bb * 16 + h) * 128 + (c - 128)) * 2048 + s] = v;
        }
      }
  }
}

// ---------------------------------------------------------------------------
// fused fp32 -> bf16 cast of hidden + all 5 weights (one launch)
// ---------------------------------------------------------------------------
__global__ __launch_bounds__(256) void cast_all(
    const float* __restrict__ hidden, const float* __restrict__ Wqd,
    const float* __restrict__ Wqu, const float* __restrict__ Wkvu,
    const float* __restrict__ Wo, const float* __restrict__ Wkvd,
    short* __restrict__ hb, short* __restrict__ Wqd_b, short* __restrict__ Wqu_b,
    short* __restrict__ Wkvu_b, short* __restrict__ Wo_b, short* __restrict__ Wkvd_b)
{
  int blk = blockIdx.x;
  const float* src; short* dst; int i;
  if (blk < 8192)       { src = hidden; dst = hb;     i = (blk * 256 + threadIdx.x) * 4; }
  else if (blk < 11264) { src = Wqd;  dst = Wqd_b;  i = ((blk - 8192) * 256 + threadIdx.x) * 4; }
  else if (blk < 15872) { src = Wqu;  dst = Wqu_b;  i = ((blk - 11264) * 256 + threadIdx.x) * 4; }
  else if (blk < 17920) { src = Wkvu; dst = Wkvu_b; i = ((blk - 15872) * 256 + threadIdx.x) * 4; }
  else if (blk < 22016) { src = Wo;   dst = Wo_b;   i = ((blk - 17920) * 256 + threadIdx.x) * 4; }
  else {
    i = ((blk - 22016) * 256 + threadIdx.x) * 4;
    int r = i >> 11;
    short4 o = {0, 0, 0, 0};
    if (r < 576) {
      float4 v = *(const float4*)(Wkvd + i);
      o.x = f2bf(v.x); o.y = f2bf(v.y); o.z = f2bf(v.z); o.w = f2bf(v.w);
    }
    *(short4*)(Wkvd_b + i) = o;
    return;
  }
  float4 v = *(const float4*)(src + i);
  short4 o = { f2bf(v.x), f2bf(v.y), f2bf(v.z), f2bf(v.w) };
  *(short4*)(dst + i) = o;
}

// ---------------------------------------------------------------------------
__global__ __launch_bounds__(256) void rmsnorm_cast(
    const float* __restrict__ X, const float* __restrict__ gamma,
    short* __restrict__ Y, int C, int sx, int sy)
{
  const float* x = X + (size_t)blockIdx.x * sx;
  short* y = Y + (size_t)blockIdx.x * sy;
  const int tid = threadIdx.x;
  float ss = 0.f;
  for (int c = tid * 4; c < C; c += 1024) {
    float4 v = *(const float4*)(x + c);
    ss += v.x * v.x + v.y * v.y + v.z * v.z + v.w * v.w;
  }
  #pragma unroll
  for (int off = 32; off > 0; off >>= 1) ss += __shfl_down(ss, off, 64);
  __shared__ float red[4];
  if ((tid & 63) == 0) red[tid >> 6] = ss;
  __syncthreads();
  float tot = red[0] + red[1] + red[2] + red[3];
  float scale = rsqrtf(tot / (float)C + 1e-6f);
  for (int c = tid * 4; c < C; c += 1024) {
    float4 v = *(const float4*)(x + c);
    float4 g = *(const float4*)(gamma + c);
    short4 o = { f2bf(v.x * scale * g.x), f2bf(v.y * scale * g.y),
                 f2bf(v.z * scale * g.z), f2bf(v.w * scale * g.w) };
    *(short4*)(y + c) = o;
  }
}

// ---------------------------------------------------------------------------
__global__ __launch_bounds__(256) void rmsnorm_kv_rope(
    const float* __restrict__ kvf, const float* __restrict__ gamma,
    const float* __restrict__ cosb, const float* __restrict__ sinb,
    short* __restrict__ ckv, short* __restrict__ kr)
{
  const int m = blockIdx.x;
  const float* x = kvf + (size_t)m * 640;
  short* y = ckv + (size_t)m * 512;
  const int tid = threadIdx.x;
  float ss = 0.f;
  for (int c = tid * 4; c < 512; c += 1024) {
    float4 v = *(const float4*)(x + c);
    ss += v.x * v.x + v.y * v.y + v.z * v.z + v.w * v.w;
  }
  #pragma unroll
  for (int off = 32; off > 0; off >>= 1) ss += __shfl_down(ss, off, 64);
  __shared__ float red[4];
  if ((tid & 63) == 0) red[tid >> 6] = ss;
  __syncthreads();
  float tot = red[0] + red[1] + red[2] + red[3];
  float scale = rsqrtf(tot / 512.f + 1e-6f);
  for (int c = tid * 4; c < 512; c += 1024) {
    float4 v = *(const float4*)(x + c);
    float4 g = *(const float4*)(gamma + c);
    short4 o = { f2bf(v.x * scale * g.x), f2bf(v.y * scale * g.y),
                 f2bf(v.z * scale * g.z), f2bf(v.w * scale * g.w) };
    *(short4*)(y + c) = o;
  }
  if (tid < 32) {
    const float* cb = cosb + (size_t)m * 64;
    const float* sb = sinb + (size_t)m * 64;
    float x1 = x[512 + tid], x2 = x[512 + tid + 32];
    kr[(size_t)m * 64 + tid]      = f2bf(x1 * cb[tid] - x2 * sb[tid]);
    kr[(size_t)m * 64 + tid + 32] = f2bf(x2 * cb[tid + 32] + x1 * sb[tid + 32]);
  }
}

// ---------------------------------------------------------------------------
__global__ __launch_bounds__(256) void krope_fill(
    const short* __restrict__ kr, short* __restrict__ Kb)
{
  int m = blockIdx.x;
  int b = m >> 11, s = m & 2047;
  for (int idx = threadIdx.x; idx < 1024; idx += 256) {
    int h = idx >> 6, j = idx & 63;
    Kb[(((size_t)(b * 16 + h)) * 2048 + s) * 192 + 128 + j] = kr[(size_t)m * 64 + j];
  }
}

// ---------------------------------------------------------------------------
// MFMA flash attention v9 = v7 sync structure (known-good: dbuf K/V, all-wave
// staging, ONE __syncthreads per iter) + conflict-free lane-linear frags.
// - LDS frag layout: 1KB frag holds a 16-row x 32-col bf16 tile; byte lane*16
//   = [row lane&15][kchunk lane>>4] -> read addr frag*1024 + lane*16 is
//   linear (v7 read pattern was ~8-way bank-conflicted: 6.9M conflicts).
//   Achieved by pre-permuting the per-lane GLOBAL source of global_load_lds
//   (m173): dst stays tid-linear, src row=lane&15, col chunk=lane>>4.
// - causal-complement pair per block (balanced 136 wave-iters/block).
// ---------------------------------------------------------------------------
#define PSTR 72

__global__ __launch_bounds__(512) void flash_mfma(
    const short* __restrict__ Qb, const short* __restrict__ Kb,
    const short* __restrict__ Vt, short* __restrict__ attnb)
{
  __shared__ __align__(16) short KsF[2][24 * 512];   // 49.2 KB, lane-linear frags
  __shared__ __align__(16) short VsF[2][16 * 512];   // 32.8 KB
  __shared__ __align__(16) short Ps[8][32 * PSTR];   // 36.9 KB (total 118.8 KB)

  const int h = blockIdx.x;                          // XCD locality: id%8 = h%8
  const int p = blockIdx.y;                          // pair index 0..7
  const int b = blockIdx.z;
  const int bh = b * 16 + h;
  const int tid = threadIdx.x;
  const int wave = tid >> 6, lane = tid & 63;
  const int grp = wave >> 2, w4 = wave & 3;          // grp 0 = heavy, 1 = light
  const int quad = lane >> 4, n16 = lane & 15;
  const int qt = grp ? p : (15 - p);
  const int qw = qt * 128 + w4 * 32;
  const int nkt = 2 * (15 - p) + 2;                  // heavy member governs loop

  // ---- staging tables: 3 K-chunks + 2 V-chunks of 1KB per wave ----
  // K chunk c = wave*3+u (ct=c/6, t=c%6): lane sources
  //   K[ct*16 + (lane&15)][t*32 + (lane>>4)*8 ..+8]  -> frag byte lane*16.
  // V chunk ci = wave*2+u (ks=ci>>3, vt=ci&7): lane sources
  //   Vt[vt*16 + (lane&15)][ks*32 + (lane>>4)*8 ..+8].
  const short* kSrc[3];
  short* kDst[3];
  #pragma unroll
  for (int u = 0; u < 3; ++u) {
    int c = wave * 3 + u;
    int ct = c / 6, t = c - ct * 6;
    kSrc[u] = Kb + ((size_t)bh * 2048 + ct * 16 + (lane & 15)) * 192 + t * 32 + (lane >> 4) * 8;
    kDst[u] = &KsF[0][c * 512 + lane * 8];
  }
  const short* vSrc[2];
  short* vDst[2];
  #pragma unroll
  for (int u = 0; u < 2; ++u) {
    int ci = wave * 2 + u, ks = ci >> 3, vt = ci & 7;
    vSrc[u] = Vt + ((size_t)bh * 128 + vt * 16 + (lane & 15)) * 2048 + ks * 32 + (lane >> 4) * 8;
    vDst[u] = &VsF[0][ci * 512 + lane * 8];
  }
  const int kbufS = 24 * 512;     // shorts per K buffer
  const int vbufS = 16 * 512;

  // Q A-frags (used as MFMA B operand for S^T): 2 row-groups x 6 k-slices
  bf16x8 aQ[2][6];
  #pragma unroll
  for (int rg = 0; rg < 2; ++rg) {
    const short* qp = Qb + ((size_t)bh * 2048 + qw + rg * 16 + n16) * 192 + quad * 8;
    #pragma unroll
    for (int t = 0; t < 6; ++t) aQ[rg][t] = *(const bf16x8*)(qp + t * 32);
  }

  f32x4 O[2][8];
  #pragma unroll
  for (int rg = 0; rg < 2; ++rg)
    #pragma unroll
    for (int i = 0; i < 8; ++i) O[rg][i] = (f32x4){0.f, 0.f, 0.f, 0.f};
  float lp[2] = {0.f, 0.f};    // per-lane partial l for q = qw + rg*16 + n16

  short* pw = &Ps[wave][0];

  // prologue: stage kt=0 into buffer 0
  #pragma unroll
  for (int u = 0; u < 3; ++u) gl_lds16(kSrc[u], kDst[u]);
  #pragma unroll
  for (int u = 0; u < 2; ++u) gl_lds16(vSrc[u], vDst[u]);
  __syncthreads();

  for (int kt = 0; kt < nkt; ++kt) {
    const int db = kt & 1;

    // ---- issue stage of kt+1 into the other buffer (drained at barrier) ----
    if (kt + 1 < nkt) {
      const int dn = db ^ 1;
      #pragma unroll
      for (int u = 0; u < 3; ++u)
        gl_lds16(kSrc[u] + (size_t)(kt + 1) * 64 * 192, kDst[u] + dn * kbufS);
      #pragma unroll
      for (int u = 0; u < 2; ++u)
        gl_lds16(vSrc[u] + (size_t)(kt + 1) * 64, vDst[u] + dn * vbufS);
    }

    if (kt * 64 <= qw + 31) {
      // ---- S^T = K·Q^T: per ct (16 keys), per rg (16 q) ----
      float s[4][2][4];
      bool act[4];
      const bool tail = (kt * 64 + 63 > qw);
      #pragma unroll
      for (int ct = 0; ct < 4; ++ct) {
        act[ct] = (kt * 64 + ct * 16 <= qw + 31);
        if (act[ct]) {
          f32x4 a0 = (f32x4){0.f, 0.f, 0.f, 0.f};
          f32x4 a1 = (f32x4){0.f, 0.f, 0.f, 0.f};
          #pragma unroll
          for (int t = 0; t < 6; ++t) {
            bf16x8 ak = *(const bf16x8*)&KsF[db][(ct * 6 + t) * 512 + lane * 8];
            a0 = __builtin_amdgcn_mfma_f32_16x16x32_bf16(ak, aQ[0][t], a0, 0, 0, 0);
            a1 = __builtin_amdgcn_mfma_f32_16x16x32_bf16(ak, aQ[1][t], a1, 0, 0, 0);
          }
          #pragma unroll
          for (int r = 0; r < 4; ++r) { s[ct][0][r] = a0[r]; s[ct][1][r] = a1[r]; }
        }
      }

      // ---- exp + mask + accumulate l + packed P store (b64) ----
      #pragma unroll
      for (int rg = 0; rg < 2; ++rg) {
        const int q = qw + rg * 16 + n16;
        #pragma unroll
        for (int ct = 0; ct < 4; ++ct) {
          u16x4 pk;
          #pragma unroll
          for (int r = 0; r < 4; ++r) {
            float v = 0.f;
            if (act[ct]) {
              v = __expf(s[ct][rg][r]);
              if (tail) {
                int key = kt * 64 + ct * 16 + quad * 4 + r;
                if (key > q) v = 0.f;
              }
            }
            lp[rg] += v;
            pk[r] = (unsigned short)f2bf(v);
          }
          *(u16x4*)&pw[(rg * 16 + n16) * PSTR + ct * 16 + quad * 4] = pk;
        }
      }

      // ---- PV: O[32x128] += P[32x64] @ V[64x128] ----
      #pragma unroll
      for (int ks = 0; ks < 2; ++ks) {
        if (kt * 64 + ks * 32 <= qw + 31) {
          bf16x8 aP0 = *(const bf16x8*)&pw[(n16) * PSTR + ks * 32 + quad * 8];
          bf16x8 aP1 = *(const bf16x8*)&pw[(16 + n16) * PSTR + ks * 32 + quad * 8];
          #pragma unroll
          for (int vt = 0; vt < 8; ++vt) {
            bf16x8 bV = *(const bf16x8*)&VsF[db][(ks * 8 + vt) * 512 + lane * 8];
            O[0][vt] = __builtin_amdgcn_mfma_f32_16x16x32_bf16(aP0, bV, O[0][vt], 0, 0, 0);
            O[1][vt] = __builtin_amdgcn_mfma_f32_16x16x32_bf16(aP1, bV, O[1][vt], 0, 0, 0);
          }
        }
      }
    }

    __syncthreads();   // drains kt+1 DMA (post-compute) + protects buffers
  }

  // ---- epilogue: reduce l over quads, scale, store ----
  #pragma unroll
  for (int rg = 0; rg < 2; ++rg) {
    float l = lp[rg];
    l += __shfl_xor(l, 16);
    l += __shfl_xor(l, 32);          // all quads now hold l for q = qw+rg*16+n16
    float inv_l[4];
    #pragma unroll
    for (int r = 0; r < 4; ++r)
      inv_l[r] = 1.f / __shfl(l, quad * 4 + r);   // l for q-local = quad*4+r
    #pragma unroll
    for (int vt = 0; vt < 8; ++vt)
      #pragma unroll
      for (int r = 0; r < 4; ++r) {
        size_t m = (size_t)b * 2048 + qw + rg * 16 + quad * 4 + r;
        attnb[(m * 16 + h) * 128 + vt * 16 + n16] = f2bf(O[rg][vt][r] * inv_l[r]);
      }
  }
}

// ---------------------------------------------------------------------------
extern "C" void kernel_launch(void* const* d_in, const int* in_sizes, int n_in,
                              void* d_out, int out_size, void* d_ws, size_t ws_size,
                              hipStream_t stream)
{
  const float* hidden   = (const float*)d_in[0];
  const float* cosb     = (const float*)d_in[1];
  const float* sinb     = (const float*)d_in[2];
  const float* Wq_down  = (const float*)d_in[3];
  const float* q_gamma  = (const float*)d_in[4];
  const float* Wq_up    = (const float*)d_in[5];
  const float* Wkv_down = (const float*)d_in[6];
  const float* kv_gamma = (const float*)d_in[7];
  const float* Wkv_up   = (const float*)d_in[8];
  const float* Wo       = (const float*)d_in[9];
  float* out = (float*)d_out;

  // ---- workspace (117 MB, aliased; liveness as rounds 5-7) ----
  char* base = (char*)d_ws;
  short* hb  = (short*)base;
  float* kvf = (float*)(base + 16777216);
  short* Qb  = (short*)base;
  char* pB = base + 27262976;
  short* Wqd_b  = (short*)pB;
  short* Wkvd_b = (short*)(pB + 6291456);
  short* Wqu_b  = (short*)(pB + 8912896);
  short* Wkvu_b = (short*)(pB + 18350080);
  short* Wo_b   = (short*)(pB + 22544384);
  char* pC = pB + 30932992;
  float* q_lat = (float*)pC;
  short* Kb    = (short*)pC;
  char* pD = pC + 25165824;
  short* q_lat_b = (short*)pD;
  short* ckv_b   = (short*)(pD + 12582912);
  short* krope_b = (short*)(pD + 16777216);
  short* attn_b  = (short*)pD;
  char* pE = pD + 17301504;
  short* Vt = (short*)pE;

  dim3 blk(256);

  cast_all<<<23296, blk, 0, stream>>>(hidden, Wq_down, Wq_up, Wkv_up, Wo, Wkv_down,
                                      hb, Wqd_b, Wqu_b, Wkvu_b, Wo_b, Wkvd_b);

  gemm_mfma<0><<<dim3(12, 32), blk, 0, stream>>>(hb, Wqd_b, q_lat, 1536, 2048, nullptr, nullptr, nullptr);
  gemm_mfma<0><<<dim3(5, 32), blk, 0, stream>>>(hb, Wkvd_b, kvf, 640, 2048, nullptr, nullptr, nullptr);

  rmsnorm_cast<<<4096, blk, 0, stream>>>(q_lat, q_gamma, q_lat_b, 1536, 1536, 1536);
  rmsnorm_kv_rope<<<4096, blk, 0, stream>>>(kvf, kv_gamma, cosb, sinb, ckv_b, krope_b);

  gemm_mfma<2><<<dim3(24, 32), blk, 0, stream>>>(q_lat_b, Wqu_b, Qb, 3072, 1536, cosb, sinb, nullptr);
  gemm_mfma<3><<<dim3(32, 32), blk, 0, stream>>>(ckv_b, Wkvu_b, Kb, 4096, 512, nullptr, nullptr, Vt);
  krope_fill<<<4096, blk, 0, stream>>>(krope_b, Kb);

  flash_mfma<<<dim3(16, 8, 2), dim3(512), 0, stream>>>(Qb, Kb, Vt, attn_b);
  gemm_mfma<0><<<dim3(16, 32), blk, 0, stream>>>(attn_b, Wo_b, out, 2048, 2048, nullptr, nullptr, nullptr);
}

// Round 4
// 515.075 us; speedup vs baseline: 1.1887x; 1.1887x over previous
//
#include <hip/hip_runtime.h>
#include <math.h>

#define SCALE_F 0.0721687836487032f  // 192^-0.5

typedef __attribute__((ext_vector_type(8))) short bf16x8;
typedef __attribute__((ext_vector_type(4))) float f32x4;
typedef __attribute__((ext_vector_type(4))) unsigned short u16x4;

static __device__ __forceinline__ short f2bf(float f) {
  unsigned u = __float_as_uint(f);
  u += 0x7fffu + ((u >> 16) & 1u);   // RNE
  return (short)(u >> 16);
}

// async global->LDS, 16B per lane (m97-verified path)
static __device__ __forceinline__ void gl_lds16(const void* g, void* l) {
  __builtin_amdgcn_global_load_lds((const __attribute__((address_space(1))) void*)g,
                                   (__attribute__((address_space(3))) void*)l, 16, 0, 0);
}

// ---------------------------------------------------------------------------
// bf16 MFMA GEMM (m97 structure, R1-verified staging): C = A[M,K] @ W[N,K]^T
// MODE 0: fp32 out row-major [M][N]
// MODE 2: q_up fused rope+scale+pack -> Qb (b,h,s,192) bf16   (N=3072)
// MODE 3: kv_up fused split -> Kb (b,h,s,192) nope cols + Vt (b,h,128,2048)
// ---------------------------------------------------------------------------
template <int MODE>
__global__ __launch_bounds__(256) void gemm_mfma(
    const short* __restrict__ A, const short* __restrict__ W,
    void* __restrict__ Cout, int N, int K,
    const float* __restrict__ cosb, const float* __restrict__ sinb,
    short* __restrict__ out2)
{
  __shared__ __align__(16) short As[128 * 32];
  __shared__ __align__(16) short Ws[128 * 32];
  const int tid = threadIdx.x;
  const int lane = tid & 63;
  const int quad = lane >> 4, n16 = lane & 15;
  const int bm = blockIdx.y * 128, bn = blockIdx.x * 128;
  const int wr = ((tid >> 6) >> 1) * 64, wc = ((tid >> 6) & 1) * 64;

  f32x4 acc[4][4];
  #pragma unroll
  for (int i = 0; i < 4; ++i)
    #pragma unroll
    for (int j = 0; j < 4; ++j) acc[i][j] = (f32x4){0.f, 0.f, 0.f, 0.f};

  const int r0 = tid >> 2, c0 = (tid & 3) * 8;
  const short* a0p = A + (size_t)(bm + r0) * K + c0;
  const short* a1p = A + (size_t)(bm + 64 + r0) * K + c0;
  const short* w0p = W + (size_t)(bn + r0) * K + c0;
  const short* w1p = W + (size_t)(bn + 64 + r0) * K + c0;
  short* asd0 = &As[tid * 8];
  short* asd1 = &As[2048 + tid * 8];
  short* wsd0 = &Ws[tid * 8];
  short* wsd1 = &Ws[2048 + tid * 8];

  for (int k0 = 0; k0 < K; k0 += 32) {
    gl_lds16(a0p, asd0);
    gl_lds16(a1p, asd1);
    gl_lds16(w0p, wsd0);
    gl_lds16(w1p, wsd1);
    a0p += 32; a1p += 32; w0p += 32; w1p += 32;
    __syncthreads();

    bf16x8 af[4], wf[4];
    #pragma unroll
    for (int i = 0; i < 4; ++i) {
      af[i] = *(const bf16x8*)&As[(wr + i * 16 + n16) * 32 + quad * 8];
      wf[i] = *(const bf16x8*)&Ws[(wc + i * 16 + n16) * 32 + quad * 8];
    }
    #pragma unroll
    for (int i = 0; i < 4; ++i)
      #pragma unroll
      for (int j = 0; j < 4; ++j)
        acc[i][j] = __builtin_amdgcn_mfma_f32_16x16x32_bf16(af[i], wf[j], acc[i][j], 0, 0, 0);
    __syncthreads();
  }

  if (MODE == 0) {
    #pragma unroll
    for (int i = 0; i < 4; ++i)
      #pragma unroll
      for (int r = 0; r < 4; ++r) {
        size_t row = (size_t)(bm + wr + i * 16 + quad * 4 + r);
        #pragma unroll
        for (int j = 0; j < 4; ++j)
          ((float*)Cout)[row * N + bn + wc + j * 16 + n16] = acc[i][j][r];
      }
  } else if (MODE == 2) {
    // q_up: rope last 64 of each 192-head, scale, pack to (b,h,s,192)
    #pragma unroll
    for (int i = 0; i < 4; ++i)
      #pragma unroll
      for (int r = 0; r < 4; ++r) {
        int m = bm + wr + i * 16 + quad * 4 + r;
        int bb = m >> 11, s = m & 2047;
        #pragma unroll
        for (int j = 0; j < 4; ++j) {
          int col = bn + wc + j * 16 + n16;
          int h = col / 192, c = col - h * 192;
          float v = acc[i][j][r];
          if (c >= 128) {
            int jr = c - 128;
            float part = acc[i][j ^ 2][r];   // partner col = col +/- 32 (in-wave)
            float cs = cosb[(size_t)m * 64 + jr], sn = sinb[(size_t)m * 64 + jr];
            v = (jr < 32) ? (v * cs - part * sn) : (v * cs + part * sn);
          }
          ((short*)Cout)[(((size_t)(bb * 16 + h)) * 2048 + s) * 192 + c] = f2bf(v * SCALE_F);
        }
      }
  } else {
    // kv_up: N=4096, head = col>>8; c<128 -> Kb nope, c>=128 -> Vt transposed
    #pragma unroll
    for (int i = 0; i < 4; ++i)
      #pragma unroll
      for (int r = 0; r < 4; ++r) {
        int m = bm + wr + i * 16 + quad * 4 + r;
        int bb = m >> 11, s = m & 2047;
        #pragma unroll
        for (int j = 0; j < 4; ++j) {
          int col = bn + wc + j * 16 + n16;
          int h = col >> 8, c = col & 255;
          short v = f2bf(acc[i][j][r]);
          if (c < 128)
            ((short*)Cout)[(((size_t)(bb * 16 + h)) * 2048 + s) * 192 + c] = v;
          else
            out2[((size_t)(bb * 16 + h) * 128 + (c - 128)) * 2048 + s] = v;
        }
      }
  }
}

// ---------------------------------------------------------------------------
// fused fp32 -> bf16 cast of hidden + all 5 weights (one launch)
// ---------------------------------------------------------------------------
__global__ __launch_bounds__(256) void cast_all(
    const float* __restrict__ hidden, const float* __restrict__ Wqd,
    const float* __restrict__ Wqu, const float* __restrict__ Wkvu,
    const float* __restrict__ Wo, const float* __restrict__ Wkvd,
    short* __restrict__ hb, short* __restrict__ Wqd_b, short* __restrict__ Wqu_b,
    short* __restrict__ Wkvu_b, short* __restrict__ Wo_b, short* __restrict__ Wkvd_b)
{
  int blk = blockIdx.x;
  const float* src; short* dst; int i;
  if (blk < 8192)       { src = hidden; dst = hb;     i = (blk * 256 + threadIdx.x) * 4; }
  else if (blk < 11264) { src = Wqd;  dst = Wqd_b;  i = ((blk - 8192) * 256 + threadIdx.x) * 4; }
  else if (blk < 15872) { src = Wqu;  dst = Wqu_b;  i = ((blk - 11264) * 256 + threadIdx.x) * 4; }
  else if (blk < 17920) { src = Wkvu; dst = Wkvu_b; i = ((blk - 15872) * 256 + threadIdx.x) * 4; }
  else if (blk < 22016) { src = Wo;   dst = Wo_b;   i = ((blk - 17920) * 256 + threadIdx.x) * 4; }
  else {
    i = ((blk - 22016) * 256 + threadIdx.x) * 4;
    int r = i >> 11;
    short4 o = {0, 0, 0, 0};
    if (r < 576) {
      float4 v = *(const float4*)(Wkvd + i);
      o.x = f2bf(v.x); o.y = f2bf(v.y); o.z = f2bf(v.z); o.w = f2bf(v.w);
    }
    *(short4*)(Wkvd_b + i) = o;
    return;
  }
  float4 v = *(const float4*)(src + i);
  short4 o = { f2bf(v.x), f2bf(v.y), f2bf(v.z), f2bf(v.w) };
  *(short4*)(dst + i) = o;
}

// ---------------------------------------------------------------------------
__global__ __launch_bounds__(256) void rmsnorm_cast(
    const float* __restrict__ X, const float* __restrict__ gamma,
    short* __restrict__ Y, int C, int sx, int sy)
{
  const float* x = X + (size_t)blockIdx.x * sx;
  short* y = Y + (size_t)blockIdx.x * sy;
  const int tid = threadIdx.x;
  float ss = 0.f;
  for (int c = tid * 4; c < C; c += 1024) {
    float4 v = *(const float4*)(x + c);
    ss += v.x * v.x + v.y * v.y + v.z * v.z + v.w * v.w;
  }
  #pragma unroll
  for (int off = 32; off > 0; off >>= 1) ss += __shfl_down(ss, off, 64);
  __shared__ float red[4];
  if ((tid & 63) == 0) red[tid >> 6] = ss;
  __syncthreads();
  float tot = red[0] + red[1] + red[2] + red[3];
  float scale = rsqrtf(tot / (float)C + 1e-6f);
  for (int c = tid * 4; c < C; c += 1024) {
    float4 v = *(const float4*)(x + c);
    float4 g = *(const float4*)(gamma + c);
    short4 o = { f2bf(v.x * scale * g.x), f2bf(v.y * scale * g.y),
                 f2bf(v.z * scale * g.z), f2bf(v.w * scale * g.w) };
    *(short4*)(y + c) = o;
  }
}

// ---------------------------------------------------------------------------
__global__ __launch_bounds__(256) void rmsnorm_kv_rope(
    const float* __restrict__ kvf, const float* __restrict__ gamma,
    const float* __restrict__ cosb, const float* __restrict__ sinb,
    short* __restrict__ ckv, short* __restrict__ kr)
{
  const int m = blockIdx.x;
  const float* x = kvf + (size_t)m * 640;
  short* y = ckv + (size_t)m * 512;
  const int tid = threadIdx.x;
  float ss = 0.f;
  for (int c = tid * 4; c < 512; c += 1024) {
    float4 v = *(const float4*)(x + c);
    ss += v.x * v.x + v.y * v.y + v.z * v.z + v.w * v.w;
  }
  #pragma unroll
  for (int off = 32; off > 0; off >>= 1) ss += __shfl_down(ss, off, 64);
  __shared__ float red[4];
  if ((tid & 63) == 0) red[tid >> 6] = ss;
  __syncthreads();
  float tot = red[0] + red[1] + red[2] + red[3];
  float scale = rsqrtf(tot / 512.f + 1e-6f);
  for (int c = tid * 4; c < 512; c += 1024) {
    float4 v = *(const float4*)(x + c);
    float4 g = *(const float4*)(gamma + c);
    short4 o = { f2bf(v.x * scale * g.x), f2bf(v.y * scale * g.y),
                 f2bf(v.z * scale * g.z), f2bf(v.w * scale * g.w) };
    *(short4*)(y + c) = o;
  }
  if (tid < 32) {
    const float* cb = cosb + (size_t)m * 64;
    const float* sb = sinb + (size_t)m * 64;
    float x1 = x[512 + tid], x2 = x[512 + tid + 32];
    kr[(size_t)m * 64 + tid]      = f2bf(x1 * cb[tid] - x2 * sb[tid]);
    kr[(size_t)m * 64 + tid + 32] = f2bf(x2 * cb[tid + 32] + x1 * sb[tid + 32]);
  }
}

// ---------------------------------------------------------------------------
__global__ __launch_bounds__(256) void krope_fill(
    const short* __restrict__ kr, short* __restrict__ Kb)
{
  int m = blockIdx.x;
  int b = m >> 11, s = m & 2047;
  for (int idx = threadIdx.x; idx < 1024; idx += 256) {
    int h = idx >> 6, j = idx & 63;
    Kb[(((size_t)(b * 16 + h)) * 2048 + s) * 192 + 128 + j] = kr[(size_t)m * 64 + j];
  }
}

// ---------------------------------------------------------------------------
// MFMA flash attention v10: split-kt balanced schedule.
// Fixed-shift softmax (exp(s), no running max) makes O and l PURE SUMS over
// kt -> the kt range is associative and can be split across wave groups:
//   grp0 (waves 0-3): heavy tile qt=15-p, kt in [0,17)
//   grp1 (waves 4-7): light tile qt=p fully (kt in [0,2p+2)), then heavy
//                     tile kt in [17, 32-2p)
// Per-wave iterations = 17 for EVERY wave of EVERY block -> critical path
// 32 -> 17 iters and 2 compute-waves/SIMD at all times.
// Each group streams its own kt -> per-group K/V LDS region (single-buffered,
// 2x40KB) + Ps (36.9KB) = 117KB. Plain __syncthreads x2 per iter; both
// groups always reach every barrier (no divergent-barrier risk).
// grp1 stores its finished light tile mid-loop; its heavy partial (O,l) is
// lane-congruent with grp0's and combined via LDS in the epilogue.
// ---------------------------------------------------------------------------
#define PSTR 72

__global__ __launch_bounds__(512) void flash_mfma(
    const short* __restrict__ Qb, const short* __restrict__ Kb,
    const short* __restrict__ Vt, short* __restrict__ attnb)
{
  __shared__ __align__(16) short KVs[2][40 * 512];   // per group: 24 K + 16 V chunks (80 KB)
  __shared__ __align__(16) short Ps[8][32 * PSTR];   // 36.9 KB   (total 116.9 KB)

  const int h = blockIdx.x;                          // XCD locality: id%8 = h%8
  const int p = blockIdx.y;                          // pair index 0..7
  const int b = blockIdx.z;
  const int bh = b * 16 + h;
  const int tid = threadIdx.x;
  const int wave = tid >> 6, lane = tid & 63;
  const int grp = wave >> 2, w4 = wave & 3;          // grp0 heavy / grp1 light->heavy
  const int quad = lane >> 4, n16 = lane & 15;
  const int lq = lane >> 2, lr = lane & 3;           // staging lane split
  const int qt_h = 15 - p;
  const int L = 2 * p + 2;                           // light-tile iteration count
  const int NIT = 17;                                // iterations for every wave

  int qw = (grp ? p : qt_h) * 128 + w4 * 32;         // current tile q-window

  // ---- staging tables: per group, 4 waves stage 24 K + 16 V chunks ----
  // K: wave w4 stages rows w4*16+lq, 6 col-chunks u (cols u*32 + lr*8).
  // V: chunk ci = w4*4+u (ks=ci>>3, vt=ci&7): rows vt*16+lq of Vt.
  const short* kS[6]; short* kD[6];
  #pragma unroll
  for (int u = 0; u < 6; ++u) {
    kS[u] = Kb + ((size_t)bh * 2048 + w4 * 16 + lq) * 192 + u * 32 + lr * 8;
    kD[u] = &KVs[grp][(w4 * 6 + u) * 512 + lane * 8];
  }
  const short* vS[4]; short* vD[4];
  #pragma unroll
  for (int u = 0; u < 4; ++u) {
    int ci = w4 * 4 + u, ks = ci >> 3, vt = ci & 7;
    vS[u] = Vt + ((size_t)bh * 128 + vt * 16 + lq) * 2048 + ks * 32 + lr * 8;
    vD[u] = &KVs[grp][(24 + ci) * 512 + lane * 8];
  }

  // Q A-frags for current tile: 2 row-groups x 6 k-slices
  bf16x8 aQ[2][6];
  #pragma unroll
  for (int rg = 0; rg < 2; ++rg) {
    const short* qp = Qb + ((size_t)bh * 2048 + qw + rg * 16 + n16) * 192 + quad * 8;
    #pragma unroll
    for (int t = 0; t < 6; ++t) aQ[rg][t] = *(const bf16x8*)(qp + t * 32);
  }

  f32x4 O[2][8];
  #pragma unroll
  for (int rg = 0; rg < 2; ++rg)
    #pragma unroll
    for (int i = 0; i < 8; ++i) O[rg][i] = (f32x4){0.f, 0.f, 0.f, 0.f};
  float lp[2] = {0.f, 0.f};

  short* pw = &Ps[wave][0];

  // stage iteration 0 (kt=0 for both groups)
  {
    #pragma unroll
    for (int u = 0; u < 6; ++u) gl_lds16(kS[u], kD[u]);
    #pragma unroll
    for (int u = 0; u < 4; ++u) gl_lds16(vS[u], vD[u]);
  }

  for (int j = 0; j < NIT; ++j) {
    __syncthreads();   // stage(j) complete (barrier drains vmcnt)

    // grp1: light tile finished -> store it, switch to heavy tail
    if (grp == 1 && j == L) {
      #pragma unroll
      for (int rg = 0; rg < 2; ++rg) {
        float l = lp[rg];
        l += __shfl_xor(l, 16);
        l += __shfl_xor(l, 32);
        float inv_l[4];
        #pragma unroll
        for (int r = 0; r < 4; ++r) inv_l[r] = 1.f / __shfl(l, quad * 4 + r);
        #pragma unroll
        for (int vt = 0; vt < 8; ++vt)
          #pragma unroll
          for (int r = 0; r < 4; ++r) {
            size_t m = (size_t)b * 2048 + qw + rg * 16 + quad * 4 + r;
            attnb[(m * 16 + h) * 128 + vt * 16 + n16] = f2bf(O[rg][vt][r] * inv_l[r]);
          }
      }
      #pragma unroll
      for (int rg = 0; rg < 2; ++rg)
        #pragma unroll
        for (int i = 0; i < 8; ++i) O[rg][i] = (f32x4){0.f, 0.f, 0.f, 0.f};
      lp[0] = 0.f; lp[1] = 0.f;
      qw = qt_h * 128 + w4 * 32;
      #pragma unroll
      for (int rg = 0; rg < 2; ++rg) {
        const short* qp = Qb + ((size_t)bh * 2048 + qw + rg * 16 + n16) * 192 + quad * 8;
        #pragma unroll
        for (int t = 0; t < 6; ++t) aQ[rg][t] = *(const bf16x8*)(qp + t * 32);
      }
    }

    const int kt = (grp == 0) ? j : (j < L ? j : 17 + j - L);

    if (kt * 64 <= qw + 31) {
      // ---- S^T = K·Q^T ----
      float s[4][2][4];
      bool act[4];
      const bool tail = (kt * 64 + 63 > qw);
      #pragma unroll
      for (int ct = 0; ct < 4; ++ct) {
        act[ct] = (kt * 64 + ct * 16 <= qw + 31);
        if (act[ct]) {
          f32x4 a0 = (f32x4){0.f, 0.f, 0.f, 0.f};
          f32x4 a1 = (f32x4){0.f, 0.f, 0.f, 0.f};
          #pragma unroll
          for (int t = 0; t < 6; ++t) {
            bf16x8 ak = *(const bf16x8*)&KVs[grp][(ct * 6 + t) * 512 + n16 * 32 + quad * 8];
            a0 = __builtin_amdgcn_mfma_f32_16x16x32_bf16(ak, aQ[0][t], a0, 0, 0, 0);
            a1 = __builtin_amdgcn_mfma_f32_16x16x32_bf16(ak, aQ[1][t], a1, 0, 0, 0);
          }
          #pragma unroll
          for (int r = 0; r < 4; ++r) { s[ct][0][r] = a0[r]; s[ct][1][r] = a1[r]; }
        }
      }

      // ---- exp + mask + accumulate l + packed P store ----
      #pragma unroll
      for (int rg = 0; rg < 2; ++rg) {
        const int q = qw + rg * 16 + n16;
        #pragma unroll
        for (int ct = 0; ct < 4; ++ct) {
          u16x4 pk;
          #pragma unroll
          for (int r = 0; r < 4; ++r) {
            float v = 0.f;
            if (act[ct]) {
              v = __expf(s[ct][rg][r]);
              if (tail) {
                int key = kt * 64 + ct * 16 + quad * 4 + r;
                if (key > q) v = 0.f;
              }
            }
            lp[rg] += v;
            pk[r] = (unsigned short)f2bf(v);
          }
          *(u16x4*)&pw[(rg * 16 + n16) * PSTR + ct * 16 + quad * 4] = pk;
        }
      }

      // ---- PV: O += P @ V ----
      #pragma unroll
      for (int ks = 0; ks < 2; ++ks) {
        if (kt * 64 + ks * 32 <= qw + 31) {
          bf16x8 aP0 = *(const bf16x8*)&pw[(n16) * PSTR + ks * 32 + quad * 8];
          bf16x8 aP1 = *(const bf16x8*)&pw[(16 + n16) * PSTR + ks * 32 + quad * 8];
          #pragma unroll
          for (int vt = 0; vt < 8; ++vt) {
            bf16x8 bV = *(const bf16x8*)&KVs[grp][(24 + ks * 8 + vt) * 512 + n16 * 32 + quad * 8];
            O[0][vt] = __builtin_amdgcn_mfma_f32_16x16x32_bf16(aP0, bV, O[0][vt], 0, 0, 0);
            O[1][vt] = __builtin_amdgcn_mfma_f32_16x16x32_bf16(aP1, bV, O[1][vt], 0, 0, 0);
          }
        }
      }
    }

    __syncthreads();   // readers of KVs[grp] done

    if (j + 1 < NIT) {
      const int jn = j + 1;
      const int ktn = (grp == 0) ? jn : (jn < L ? jn : 17 + jn - L);
      const size_t ka = (size_t)ktn * (64 * 192);
      const size_t va = (size_t)ktn * 64;
      #pragma unroll
      for (int u = 0; u < 6; ++u) gl_lds16(kS[u] + ka, kD[u]);
      #pragma unroll
      for (int u = 0; u < 4; ++u) gl_lds16(vS[u] + va, vD[u]);
    }
  }

  // ---- epilogue: combine grp1's heavy partial into grp0, store heavy ----
  float* xO = (float*)&KVs[0][0];            // 20480 floats available
  float* xl = (float*)&Ps[0][0];
  const int xb = w4 * 4160 + lane * 65;      // stride 65 -> conflict-free
  if (grp == 1) {
    #pragma unroll
    for (int rg = 0; rg < 2; ++rg)
      #pragma unroll
      for (int vt = 0; vt < 8; ++vt)
        #pragma unroll
        for (int r = 0; r < 4; ++r)
          xO[xb + rg * 32 + vt * 4 + r] = O[rg][vt][r];
    xl[w4 * 128 + lane * 2 + 0] = lp[0];
    xl[w4 * 128 + lane * 2 + 1] = lp[1];
  }
  __syncthreads();
  if (grp == 0) {
    #pragma unroll
    for (int rg = 0; rg < 2; ++rg)
      #pragma unroll
      for (int vt = 0; vt < 8; ++vt)
        #pragma unroll
        for (int r = 0; r < 4; ++r)
          O[rg][vt][r] += xO[xb + rg * 32 + vt * 4 + r];
    lp[0] += xl[w4 * 128 + lane * 2 + 0];
    lp[1] += xl[w4 * 128 + lane * 2 + 1];

    #pragma unroll
    for (int rg = 0; rg < 2; ++rg) {
      float l = lp[rg];
      l += __shfl_xor(l, 16);
      l += __shfl_xor(l, 32);
      float inv_l[4];
      #pragma unroll
      for (int r = 0; r < 4; ++r) inv_l[r] = 1.f / __shfl(l, quad * 4 + r);
      #pragma unroll
      for (int vt = 0; vt < 8; ++vt)
        #pragma unroll
        for (int r = 0; r < 4; ++r) {
          size_t m = (size_t)b * 2048 + qw + rg * 16 + quad * 4 + r;
          attnb[(m * 16 + h) * 128 + vt * 16 + n16] = f2bf(O[rg][vt][r] * inv_l[r]);
        }
    }
  }
}

// ---------------------------------------------------------------------------
extern "C" void kernel_launch(void* const* d_in, const int* in_sizes, int n_in,
                              void* d_out, int out_size, void* d_ws, size_t ws_size,
                              hipStream_t stream)
{
  const float* hidden   = (const float*)d_in[0];
  const float* cosb     = (const float*)d_in[1];
  const float* sinb     = (const float*)d_in[2];
  const float* Wq_down  = (const float*)d_in[3];
  const float* q_gamma  = (const float*)d_in[4];
  const float* Wq_up    = (const float*)d_in[5];
  const float* Wkv_down = (const float*)d_in[6];
  const float* kv_gamma = (const float*)d_in[7];
  const float* Wkv_up   = (const float*)d_in[8];
  const float* Wo       = (const float*)d_in[9];
  float* out = (float*)d_out;

  // ---- workspace (117 MB, aliased; liveness as rounds 5-7) ----
  char* base = (char*)d_ws;
  short* hb  = (short*)base;
  float* kvf = (float*)(base + 16777216);
  short* Qb  = (short*)base;
  char* pB = base + 27262976;
  short* Wqd_b  = (short*)pB;
  short* Wkvd_b = (short*)(pB + 6291456);
  short* Wqu_b  = (short*)(pB + 8912896);
  short* Wkvu_b = (short*)(pB + 18350080);
  short* Wo_b   = (short*)(pB + 22544384);
  char* pC = pB + 30932992;
  float* q_lat = (float*)pC;
  short* Kb    = (short*)pC;
  char* pD = pC + 25165824;
  short* q_lat_b = (short*)pD;
  short* ckv_b   = (short*)(pD + 12582912);
  short* krope_b = (short*)(pD + 16777216);
  short* attn_b  = (short*)pD;
  char* pE = pD + 17301504;
  short* Vt = (short*)pE;

  dim3 blk(256);

  cast_all<<<23296, blk, 0, stream>>>(hidden, Wq_down, Wq_up, Wkv_up, Wo, Wkv_down,
                                      hb, Wqd_b, Wqu_b, Wkvu_b, Wo_b, Wkvd_b);

  gemm_mfma<0><<<dim3(12, 32), blk, 0, stream>>>(hb, Wqd_b, q_lat, 1536, 2048, nullptr, nullptr, nullptr);
  gemm_mfma<0><<<dim3(5, 32), blk, 0, stream>>>(hb, Wkvd_b, kvf, 640, 2048, nullptr, nullptr, nullptr);

  rmsnorm_cast<<<4096, blk, 0, stream>>>(q_lat, q_gamma, q_lat_b, 1536, 1536, 1536);
  rmsnorm_kv_rope<<<4096, blk, 0, stream>>>(kvf, kv_gamma, cosb, sinb, ckv_b, krope_b);

  gemm_mfma<2><<<dim3(24, 32), blk, 0, stream>>>(q_lat_b, Wqu_b, Qb, 3072, 1536, cosb, sinb, nullptr);
  gemm_mfma<3><<<dim3(32, 32), blk, 0, stream>>>(ckv_b, Wkvu_b, Kb, 4096, 512, nullptr, nullptr, Vt);
  krope_fill<<<4096, blk, 0, stream>>>(krope_b, Kb);

  flash_mfma<<<dim3(16, 8, 2), dim3(512), 0, stream>>>(Qb, Kb, Vt, attn_b);
  gemm_mfma<0><<<dim3(16, 32), blk, 0, stream>>>(attn_b, Wo_b, out, 2048, 2048, nullptr, nullptr, nullptr);
}